// Round 1
// baseline (155.435 us; speedup 1.0000x reference)
//
#include <hip/hip_runtime.h>
#include <math.h>

// TopKSoftMax: rows of D=64 f32; keep top-8 (ties -> lower index, exactly as
// jax.lax.top_k), softmax over kept, zeros elsewhere (exp(-1e16-max) == 0 in f32).
//
// One thread per row. Global<->LDS staging for coalescing; XOR-swizzled float4
// slots so per-row ds_read_b128 is at the structural bank minimum.

#define D       64
#define D4      16          // float4s per row
#define ROWS    128         // rows per block
#define THREADS 128         // one thread per row; 2 waves/block; LDS 32 KB -> 5 blocks/CU

// one level of the sorted-insert chain: ti = max(ti, a); a = min(ti_old, a)
#define LVL(ti) { const float _hi = fmaxf(ti, _a); _a = fminf(ti, _a); ti = _hi; }
// insert x into t0 >= t1 >= ... >= t7 (last level needs only max)
#define INSERT(x) { float _a = (x); \
    LVL(t0) LVL(t1) LVL(t2) LVL(t3) LVL(t4) LVL(t5) LVL(t6) \
    t7 = fmaxf(t7, _a); }

// keep if strictly > thr, or == thr while index-ordered quota remains
#define PROC(x, o) { \
    const int _kgt = ((x) > thr); \
    const int _keq = ((x) == thr) & (quota > 0); \
    quota -= _keq; \
    (o) = (_kgt | _keq) ? __expf((x) - m) * inv : 0.0f; }

__global__ __launch_bounds__(THREADS)
void topk_softmax_kernel(const float* __restrict__ in,
                         float* __restrict__ out,
                         int nrows)
{
    __shared__ float4 tile[ROWS * D4];   // 32 KB, column-swizzled: slot = c ^ (r & 15)

    const int t = threadIdx.x;
    const long long base_row = (long long)blockIdx.x * ROWS;
    const float4* __restrict__ in4 = reinterpret_cast<const float4*>(in) + base_row * D4;
    float4* __restrict__ out4     = reinterpret_cast<float4*>(out) + base_row * D4;

    int rows_here = ROWS;
    if (base_row + ROWS > (long long)nrows) rows_here = (int)((long long)nrows - base_row);
    const int gmax = rows_here * D4;

    // ---- stage: global -> LDS, coalesced float4, swizzled slots ----
    #pragma unroll
    for (int i = 0; i < (ROWS * D4) / THREADS; ++i) {
        const int g = t + i * THREADS;
        if (g < gmax) {
            const float4 val = in4[g];
            const int r = g >> 4;
            const int c = g & 15;
            tile[r * D4 + (c ^ (r & 15))] = val;
        }
    }
    __syncthreads();

    if (t < rows_here) {
        const int swz = t & 15;
        float4* myrow = &tile[t * D4];

        // ---- pass 1: top-8 of this row via 8-deep compare-swap chain ----
        float t0 = -INFINITY, t1 = -INFINITY, t2 = -INFINITY, t3 = -INFINITY,
              t4 = -INFINITY, t5 = -INFINITY, t6 = -INFINITY, t7 = -INFINITY;
        #pragma unroll
        for (int c = 0; c < D4; ++c) {
            const float4 v = myrow[c ^ swz];
            INSERT(v.x) INSERT(v.y) INSERT(v.z) INSERT(v.w)
        }

        // thr = 8th order statistic; m = row max
        const float thr = t7;
        const float m  = t0;
        // elements strictly greater than thr are all inside {t0..t6}
        int quota = 8 - ((t0 > thr) + (t1 > thr) + (t2 > thr) + (t3 > thr) +
                         (t4 > thr) + (t5 > thr) + (t6 > thr));
        // kept multiset == {t0..t7}: denominator from registers (8 exps only)
        const float sum = __expf(t0 - m) + __expf(t1 - m) + __expf(t2 - m) + __expf(t3 - m) +
                          __expf(t4 - m) + __expf(t5 - m) + __expf(t6 - m) + __expf(t7 - m);
        const float inv = 1.0f / sum;

        // ---- pass 3: re-read row, write softmax back in place (index order) ----
        #pragma unroll
        for (int c = 0; c < D4; ++c) {
            const float4 v = myrow[c ^ swz];
            float4 o;
            PROC(v.x, o.x) PROC(v.y, o.y) PROC(v.z, o.z) PROC(v.w, o.w)
            myrow[c ^ swz] = o;
        }
    }
    __syncthreads();

    // ---- store: LDS -> global, coalesced float4 ----
    #pragma unroll
    for (int i = 0; i < (ROWS * D4) / THREADS; ++i) {
        const int g = t + i * THREADS;
        if (g < gmax) {
            const int r = g >> 4;
            const int c = g & 15;
            out4[g] = tile[r * D4 + (c ^ (r & 15))];
        }
    }
}

extern "C" void kernel_launch(void* const* d_in, const int* in_sizes, int n_in,
                              void* d_out, int out_size, void* d_ws, size_t ws_size,
                              hipStream_t stream) {
    const float* in = (const float*)d_in[0];
    float* out = (float*)d_out;
    const int nrows = in_sizes[0] / D;
    const int blocks = (nrows + ROWS - 1) / ROWS;
    topk_softmax_kernel<<<blocks, THREADS, 0, stream>>>(in, out, nrows);
}